// Round 12
// baseline (430.795 us; speedup 1.0000x reference)
//
#include <hip/hip_runtime.h>
#include <hip/hip_fp16.h>
#include <cstdint>
#include <cstddef>

// ---------------------------------------------------------------------------
// GIN forward, all-fp16 intermediates, fp16 MFMA GEMMs with split-fp16 W:
//  L0: gather64(x_h)->pre0; gemm(64->128,+b1,+stats)->t0; gemm(128->128,BN,+b2)->h1
//  L1: gather128(h1)->pre1; gemm(128->128,+b1,+stats)->t1; gemm(128->128,BN,+b2)->h2
//  L2: gemm(128->64)->z; gather64(z,+b1)->y; stats; gemm(64->64,BN,+b2)->out f32
// GEMM: W staged in LDS (XOR-swizzled, conflict-free ds_read_b128), A hoisted.
// CSR fill: TRUE-XCD partitioning via s_getreg(HW_REG_XCC_ID) + per-XCD chunk
// claiming (no stealing) -> cursor atomics and srcs lines stay in one L2.
// ---------------------------------------------------------------------------

static constexpr float BN_EPS_F = 1e-5f;

typedef __attribute__((ext_vector_type(8))) _Float16 f16x8;
typedef __attribute__((ext_vector_type(4))) float f32x4;

// ------------------------- CSR build kernels -------------------------------

__global__ __launch_bounds__(1024) void scan_part_kernel(const int* __restrict__ deg,
                                                         int* __restrict__ ex,
                                                         int* __restrict__ bsum, int n) {
    __shared__ int sm[1024];
    int t = threadIdx.x;
    int g = blockIdx.x * 1024 + t;
    int v = (g < n) ? deg[g] : 0;
    sm[t] = v;
    __syncthreads();
    #pragma unroll
    for (int off = 1; off < 1024; off <<= 1) {
        int x = (t >= off) ? sm[t - off] : 0;
        __syncthreads();
        sm[t] += x;
        __syncthreads();
    }
    int incl = sm[t];
    if (g < n) ex[g] = incl - v;
    if (t == 1023) bsum[blockIdx.x] = incl;
}

__global__ __launch_bounds__(128) void scan_tops_kernel(int* __restrict__ bsum, int nb) {
    __shared__ int sm[128];
    int t = threadIdx.x;
    int v = (t < nb) ? bsum[t] : 0;
    sm[t] = v;
    __syncthreads();
    #pragma unroll
    for (int off = 1; off < 128; off <<= 1) {
        int x = (t >= off) ? sm[t - off] : 0;
        __syncthreads();
        sm[t] += x;
        __syncthreads();
    }
    if (t < nb) bsum[t] = sm[t] - v;
}

__global__ __launch_bounds__(1024) void scan_add_kernel(int* __restrict__ starts,
                                                        int* __restrict__ cursor,
                                                        const int* __restrict__ bsum,
                                                        int n, int E) {
    int g = blockIdx.x * 1024 + threadIdx.x;
    if (g < n) {
        int v = starts[g] + bsum[blockIdx.x];
        starts[g] = v;
        cursor[g] = v;
    }
    if (g == 0) starts[n] = E;
}

// True-XCD fill: each block reads its hardware XCC_ID and processes ONLY that
// dst-partition, claiming chunks dynamically from pctr[xcc]. No stealing.
// Partition r's cursor range and srcs range are touched only by XCD r ->
// atomics stay L2-local, 64B srcs lines fully assemble before writeback.

__global__ __launch_bounds__(256) void fill_xcc_kernel(const int* __restrict__ src,
                                                       const int* __restrict__ dst,
                                                       int* __restrict__ cursor,
                                                       int* __restrict__ srcs,
                                                       int* __restrict__ pctr,
                                                       int E, int P, int N,
                                                       int nchunks) {
    __shared__ int s_chunk;
    int xcc;
    asm("s_getreg_b32 %0, hwreg(HW_REG_XCC_ID)" : "=s"(xcc));
    xcc &= 7;
    const int plo = xcc * P;
    const int phi = (xcc == 7) ? N : plo + P;
    const int cs = (E + nchunks - 1) / nchunks;
    while (true) {
        if (threadIdx.x == 0) s_chunk = atomicAdd(&pctr[xcc], 1);
        __syncthreads();
        const int c = s_chunk;
        __syncthreads();
        if (c >= nchunks) break;
        const int lo = c * cs;
        const int hi = (lo + cs < E) ? lo + cs : E;
        for (int e = lo + (int)threadIdx.x; e < hi; e += 256) {
            int d = dst[e];
            if (d >= plo && d < phi) {
                int q = atomicAdd(&cursor[d], 1);
                srcs[q] = src[e];
            }
        }
    }
}

// ------------------------- gather: out_h = x + sum_j x[src_j] (+bias) ------
// 1 wave per node; fp16 in/out; f32 accumulate; 4-edge clamped unroll.

template <int D, bool BIAS, bool ZSUMS>
__global__ __launch_bounds__(64) void gather_hh(const __half* __restrict__ X,
                                                const int* __restrict__ starts,
                                                const int* __restrict__ srcs,
                                                const float* __restrict__ bias,
                                                __half* __restrict__ out,
                                                float* __restrict__ sums,
                                                int nsum, int n) {
    const int node = blockIdx.x;
    const int lane = threadIdx.x;
    if (ZSUMS && node == 0) {
        for (int i = lane; i < nsum; i += 64) sums[i] = 0.f;
    }
    const int s = starts[node];
    const int e = starts[node + 1];

    if (D == 64) {
        float a = __half2float(X[(size_t)node * 64 + lane]);
        for (int j = s; j < e; j += 4) {
            int i0 = srcs[j];
            int i1 = srcs[(j + 1 < e) ? j + 1 : e - 1];
            int i2 = srcs[(j + 2 < e) ? j + 2 : e - 1];
            int i3 = srcs[(j + 3 < e) ? j + 3 : e - 1];
            float v0 = __half2float(X[(size_t)i0 * 64 + lane]);
            float v1 = __half2float(X[(size_t)i1 * 64 + lane]);
            float v2 = __half2float(X[(size_t)i2 * 64 + lane]);
            float v3 = __half2float(X[(size_t)i3 * 64 + lane]);
            a += v0;
            a += (j + 1 < e) ? v1 : 0.f;
            a += (j + 2 < e) ? v2 : 0.f;
            a += (j + 3 < e) ? v3 : 0.f;
        }
        if (BIAS) a += bias[lane];
        out[(size_t)node * 64 + lane] = __float2half(a);
    } else {
        const __half2* X2 = (const __half2*)X;  // row stride 64 half2
        float2 a = __half22float2(X2[(size_t)node * 64 + lane]);
        for (int j = s; j < e; j += 4) {
            int i0 = srcs[j];
            int i1 = srcs[(j + 1 < e) ? j + 1 : e - 1];
            int i2 = srcs[(j + 2 < e) ? j + 2 : e - 1];
            int i3 = srcs[(j + 3 < e) ? j + 3 : e - 1];
            float2 v0 = __half22float2(X2[(size_t)i0 * 64 + lane]);
            float2 v1 = __half22float2(X2[(size_t)i1 * 64 + lane]);
            float2 v2 = __half22float2(X2[(size_t)i2 * 64 + lane]);
            float2 v3 = __half22float2(X2[(size_t)i3 * 64 + lane]);
            a.x += v0.x; a.y += v0.y;
            if (j + 1 < e) { a.x += v1.x; a.y += v1.y; }
            if (j + 2 < e) { a.x += v2.x; a.y += v2.y; }
            if (j + 3 < e) { a.x += v3.x; a.y += v3.y; }
        }
        __half2* O2 = (__half2*)out;
        O2[(size_t)node * 64 + lane] = __floats2half2_rn(a.x, a.y);
    }
}

// ---- weight split (fp16 hi/lo) + histogram + x->fp16 (one launch) ---------
// cursor (+pctr) zeroed beforehand by hipMemsetAsync.

struct WsArgs {
    const float* w[6];
    short* hi[6];
    short* lo[6];
    int K[6], Nc[6], base[6];
    int total;
    const int* dstp;
    int* deg;
    int E;
    const float* xf;
    __half* xh;
    int nx4;   // N*64/4
};

__global__ __launch_bounds__(256) void wsplit_all(WsArgs a) {
    int idx = blockIdx.x * 256 + threadIdx.x;
    int stride = gridDim.x * 256;
    for (int i = idx; i < a.E; i += stride) atomicAdd(&a.deg[a.dstp[i]], 1);
    for (int i = idx; i < a.nx4; i += stride) {
        float4 v = reinterpret_cast<const float4*>(a.xf)[i];
        ushort4 o;
        o.x = __half_as_ushort(__float2half(v.x));
        o.y = __half_as_ushort(__float2half(v.y));
        o.z = __half_as_ushort(__float2half(v.z));
        o.w = __half_as_ushort(__float2half(v.w));
        reinterpret_cast<ushort4*>(a.xh)[i] = o;
    }
    for (int i = idx; i < a.total; i += stride) {
        int s = 0;
        #pragma unroll
        for (int k = 1; k < 6; ++k)
            if (i >= a.base[k]) s = k;
        int local = i - a.base[s];
        int K = a.K[s], Nc = a.Nc[s];
        int nn = local / K, kk = local - nn * K;
        float f = a.w[s][(size_t)kk * Nc + nn];
        __half h = __float2half(f);
        a.hi[s][local] = (short)__half_as_ushort(h);
        a.lo[s][local] = (short)__half_as_ushort(__float2half(f - __half2float(h)));
    }
}

// ------------------------- fp16 MFMA GEMM, W via LDS -----------------------
// C = [relu(BN(A))|A] @ (Wh+Wl) (+bias) (+stats); A fp16 [N][DI] feeds
// mfma_f32_16x16x32_f16 directly; W planes fp16 [DO][DI] staged in LDS with
// XOR swizzle (kelem ^= (row&7)<<3 on 8-half granules) so ds_read_b128 at
// row-stride DI*2B is conflict-free. Wave: 32 rows x 64 cols; block 128 rows.

template <int DI, int DO, bool BN, bool STATS, bool BIAS, bool OUTF16>
__global__ __launch_bounds__(256) void gemm16(const __half* __restrict__ A,
                                              const short* __restrict__ Wh,
                                              const short* __restrict__ Wl,
                                              const float* __restrict__ bias,
                                              const float* __restrict__ sums_in,
                                              const float* __restrict__ gvec,
                                              const float* __restrict__ bevec,
                                              float inv_n,
                                              float* __restrict__ Cf,
                                              __half* __restrict__ Ch,
                                              float* __restrict__ sums_out, int nrows) {
    constexpr int CT = DO / 64;     // column tiles
    constexpr int KI = DI / 32;
    constexpr int WCH = 64 * DI / 8;  // 16B chunks per plane
    __shared__ __align__(16) _Float16 wlds[128 * DI];  // 2 planes x 64 rows x DI
    __shared__ float s_scale[DI], s_shift[DI];
    __shared__ float ssum[64], sqsum[64];

    const int t = threadIdx.x;
    const int rowblk = blockIdx.x / CT;
    const int colbase = (blockIdx.x % CT) * 64;
    const int wave = t >> 6;
    const int lane = t & 63;
    const int lr = lane & 15;
    const int kb = lane >> 4;

    const int row_base = rowblk * 128 + wave * 32;
    const int r0 = row_base + lr;
    const int r1 = r0 + 16;
    const _Float16* a0p = (const _Float16*)A + (size_t)(r0 < nrows ? r0 : 0) * DI + kb * 8;
    const _Float16* a1p = (const _Float16*)A + (size_t)(r1 < nrows ? r1 : 0) * DI + kb * 8;

    // ---- hoisted A loads (global, overlap W staging) ----
    f16x8 a0[KI], a1[KI];
    #pragma unroll
    for (int ki = 0; ki < KI; ++ki) {
        a0[ki] = *reinterpret_cast<const f16x8*>(a0p + ki * 32);
        a1[ki] = *reinterpret_cast<const f16x8*>(a1p + ki * 32);
    }

    // ---- stage W tile (both planes) into LDS, swizzled ----
    #pragma unroll
    for (int i = 0; i < 2 * WCH / 256; ++i) {
        int c = t + i * 256;
        int plane = c / WCH;
        int rem = c - plane * WCH;
        int row = rem / (DI / 8);
        int kc = rem - row * (DI / 8);
        const _Float16* gsrc = (const _Float16*)(plane ? Wl : Wh)
                               + (size_t)(colbase + row) * DI + kc * 8;
        f16x8 v = *reinterpret_cast<const f16x8*>(gsrc);
        int koff = (kc * 8) ^ ((row & 7) << 3);
        *reinterpret_cast<f16x8*>(&wlds[(plane * 64 + row) * DI + koff]) = v;
    }

    if (BN) {
        if (t < DI) {
            float mu = sums_in[t] * inv_n;
            float var = sums_in[DI + t] * inv_n - mu * mu;
            float inv = rsqrtf(var + BN_EPS_F);
            float sc = gvec[t] * inv;
            s_scale[t] = sc;
            s_shift[t] = fmaf(-mu, sc, bevec[t]);
        }
    }
    if (STATS) {
        if (t < 64) { ssum[t] = 0.f; sqsum[t] = 0.f; }
    }
    __syncthreads();

    if (BN) {
        #pragma unroll
        for (int ki = 0; ki < KI; ++ki) {
            const int kk = ki * 32 + kb * 8;
            #pragma unroll
            for (int j = 0; j < 8; ++j) {
                float sc = s_scale[kk + j];
                float sh = s_shift[kk + j];
                a0[ki][j] = (_Float16)fmaxf(fmaf((float)a0[ki][j], sc, sh), 0.f);
                a1[ki][j] = (_Float16)fmaxf(fmaf((float)a1[ki][j], sc, sh), 0.f);
            }
        }
    }

    f32x4 acc[2][4];
    #pragma unroll
    for (int m = 0; m < 2; ++m)
        #pragma unroll
        for (int nf = 0; nf < 4; ++nf) acc[m][nf] = f32x4{0.f, 0.f, 0.f, 0.f};

    const int swz = (lr & 7) << 3;
    #pragma unroll
    for (int nf = 0; nf < 4; ++nf) {
        const int wrow = nf * 16 + lr;
        #pragma unroll
        for (int ki = 0; ki < KI; ++ki) {
            const int ke = (ki * 32 + kb * 8) ^ swz;
            f16x8 bh = *reinterpret_cast<const f16x8*>(&wlds[wrow * DI + ke]);
            f16x8 bl = *reinterpret_cast<const f16x8*>(&wlds[(64 + wrow) * DI + ke]);
            acc[0][nf] = __builtin_amdgcn_mfma_f32_16x16x32_f16(a0[ki], bh, acc[0][nf], 0, 0, 0);
            acc[0][nf] = __builtin_amdgcn_mfma_f32_16x16x32_f16(a0[ki], bl, acc[0][nf], 0, 0, 0);
            acc[1][nf] = __builtin_amdgcn_mfma_f32_16x16x32_f16(a1[ki], bh, acc[1][nf], 0, 0, 0);
            acc[1][nf] = __builtin_amdgcn_mfma_f32_16x16x32_f16(a1[ki], bl, acc[1][nf], 0, 0, 0);
        }
    }

    #pragma unroll
    for (int nf = 0; nf < 4; ++nf) {
        const int lcol = nf * 16 + lr;
        const int col = colbase + lcol;
        const float b = BIAS ? bias[col] : 0.f;
        float s = 0.f, q = 0.f;
        #pragma unroll
        for (int mf = 0; mf < 2; ++mf) {
            const int rbase = row_base + mf * 16 + kb * 4;
            #pragma unroll
            for (int reg = 0; reg < 4; ++reg) {
                const int r = rbase + reg;
                const float val = acc[mf][nf][reg] + b;
                if (r < nrows) {
                    const size_t idx = (size_t)r * DO + col;
                    if (OUTF16) Ch[idx] = __float2half(val);
                    else Cf[idx] = val;
                    if (STATS) {
                        s += val;
                        q = fmaf(val, val, q);
                    }
                }
            }
        }
        if (STATS) {
            s += __shfl_xor(s, 16);
            s += __shfl_xor(s, 32);
            q += __shfl_xor(q, 16);
            q += __shfl_xor(q, 32);
            if (lane < 16) {
                atomicAdd(&ssum[lcol], s);
                atomicAdd(&sqsum[lcol], q);
            }
        }
    }
    if (STATS) {
        __syncthreads();
        if (t < 64) {
            atomicAdd(&sums_out[colbase + t], ssum[t]);
            atomicAdd(&sums_out[DO + colbase + t], sqsum[t]);
        }
    }
}

// ------------------------- BN stats over fp16 (layer 2) --------------------

template <int DO>
__global__ __launch_bounds__(256) void stats_h(const __half* __restrict__ H,
                                               float* __restrict__ sums, int nrows) {
    constexpr int G = 256 / DO;
    int t = threadIdx.x;
    int col = t % DO;
    int grp = t / DO;
    float s = 0.f, s2 = 0.f;
    for (int r = blockIdx.x * G + grp; r < nrows; r += gridDim.x * G) {
        float v = __half2float(H[(size_t)r * DO + col]);
        s += v;
        s2 = fmaf(v, v, s2);
    }
    __shared__ float sm[256], sm2[256];
    sm[t] = s;
    sm2[t] = s2;
    __syncthreads();
    if (grp == 0) {
        #pragma unroll
        for (int g = 1; g < G; ++g) {
            s += sm[g * DO + col];
            s2 += sm2[g * DO + col];
        }
        atomicAdd(&sums[col], s);
        atomicAdd(&sums[DO + col], s2);
    }
}

// ------------------------- host orchestration ------------------------------

static inline size_t align_up(size_t v, size_t a) { return (v + a - 1) & ~(a - 1); }

extern "C" void kernel_launch(void* const* d_in, const int* in_sizes, int n_in,
                              void* d_out, int out_size, void* d_ws, size_t ws_size,
                              hipStream_t stream) {
    const float* x = (const float*)d_in[0];
    const int* ei = (const int*)d_in[1];
    const int N = in_sizes[0] / 64;
    const int E = in_sizes[1] / 2;
    const int* src = ei;
    const int* dst = ei + E;

    const float* w1[3]; const float* b1[3]; const float* gg[3];
    const float* be[3]; const float* w2[3]; const float* b2[3];
    for (int l = 0; l < 3; ++l) {
        w1[l] = (const float*)d_in[2 + 6 * l + 0];
        b1[l] = (const float*)d_in[2 + 6 * l + 1];
        gg[l] = (const float*)d_in[2 + 6 * l + 2];
        be[l] = (const float*)d_in[2 + 6 * l + 3];
        w2[l] = (const float*)d_in[2 + 6 * l + 4];
        b2[l] = (const float*)d_in[2 + 6 * l + 5];
    }

    char* ws = (char*)d_ws;
    size_t off = 0;
    auto alloc = [&](size_t bytes) {
        void* p = ws + off;
        off = align_up(off + bytes, 64);
        return p;
    };
    __half* HA   = (__half*)alloc((size_t)N * 128 * 2);  // t0 / pre1 / h2
    __half* HB   = (__half*)alloc((size_t)N * 128 * 2);  // h1 / t1
    __half* XH   = (__half*)alloc((size_t)N * 64 * 2);   // x fp16, later z
    __half* PRE0 = (__half*)alloc((size_t)N * 64 * 2);   // pre0, later y
    int* srcs   = (int*)alloc((size_t)E * 4);
    int* starts = (int*)alloc((size_t)(N + 1) * 4);
    int* cursor = (int*)alloc((size_t)(N + 8) * 4);      // +8 = pctr
    int* bsum   = (int*)alloc(256 * 4);
    float* sums = (float*)alloc(256 * 4);
    int* pctr   = cursor + N;

    const int wdims[6][2] = {{64,128},{128,128},{128,128},{128,128},{128,64},{64,64}};
    const float* wsrc[6] = {w1[0], w2[0], w1[1], w2[1], w1[2], w2[2]};
    short* wh[6]; short* wl[6];
    WsArgs wa;
    int base = 0;
    for (int i = 0; i < 6; ++i) {
        int elems = wdims[i][0] * wdims[i][1];
        wh[i] = (short*)alloc((size_t)elems * 2);
        wl[i] = (short*)alloc((size_t)elems * 2);
        wa.w[i] = wsrc[i]; wa.hi[i] = wh[i]; wa.lo[i] = wl[i];
        wa.K[i] = wdims[i][0]; wa.Nc[i] = wdims[i][1]; wa.base[i] = base;
        base += elems;
    }
    wa.total = base;
    wa.dstp = dst;
    wa.deg = cursor;
    wa.E = E;
    wa.xf = x;
    wa.xh = XH;
    wa.nx4 = N * 16;
    (void)ws_size; (void)n_in; (void)out_size;

    const float inv_n = 1.0f / (float)N;

    // ---- zero cursor+pctr; weight split + histogram + x->fp16 ----
    hipMemsetAsync(cursor, 0, (size_t)(N + 8) * 4, stream);
    wsplit_all<<<4096, 256, 0, stream>>>(wa);

    // ---- CSR scan + fill ----
    int chunks = (N + 1023) / 1024;
    scan_part_kernel<<<chunks, 1024, 0, stream>>>(cursor, starts, bsum, N);
    scan_tops_kernel<<<1, 128, 0, stream>>>(bsum, chunks);
    scan_add_kernel<<<chunks, 1024, 0, stream>>>(starts, cursor, bsum, N, E);
    int P = N / 8;
    if (P < 1) P = 1;
    fill_xcc_kernel<<<2048, 256, 0, stream>>>(src, dst, cursor, srcs, pctr,
                                              E, P, N, 256);

    const int nb = (N + 127) / 128;

    // ---- layer 0 ----
    gather_hh<64, false, true><<<N, 64, 0, stream>>>(
        XH, starts, srcs, nullptr, PRE0, sums, 256, N);
    gemm16<64, 128, false, true, true, true><<<nb * 2, 256, 0, stream>>>(
        PRE0, wh[0], wl[0], b1[0], nullptr, nullptr, nullptr, inv_n,
        nullptr, HA, sums, N);
    gemm16<128, 128, true, false, true, true><<<nb * 2, 256, 0, stream>>>(
        HA, wh[1], wl[1], b2[0], sums, gg[0], be[0], inv_n,
        nullptr, HB, nullptr, N);

    // ---- layer 1 ----
    gather_hh<128, false, true><<<N, 64, 0, stream>>>(
        HB, starts, srcs, nullptr, HA, sums, 256, N);
    gemm16<128, 128, false, true, true, true><<<nb * 2, 256, 0, stream>>>(
        HA, wh[2], wl[2], b1[1], nullptr, nullptr, nullptr, inv_n,
        nullptr, HB, sums, N);
    gemm16<128, 128, true, false, true, true><<<nb * 2, 256, 0, stream>>>(
        HB, wh[3], wl[3], b2[1], sums, gg[1], be[1], inv_n,
        nullptr, HA, nullptr, N);

    // ---- layer 2 (aggregation commuted through W1) ----
    gemm16<128, 64, false, false, false, true><<<nb, 256, 0, stream>>>(
        HA, wh[4], wl[4], nullptr, nullptr, nullptr, nullptr, inv_n,
        nullptr, XH, nullptr, N);
    gather_hh<64, true, true><<<N, 64, 0, stream>>>(
        XH, starts, srcs, b1[2], PRE0, sums, 128, N);
    stats_h<64><<<512, 256, 0, stream>>>(PRE0, sums, N);
    gemm16<64, 64, true, false, true, false><<<nb, 256, 0, stream>>>(
        PRE0, wh[5], wl[5], b2[2], sums, gg[2], be[2], inv_n,
        (float*)d_out, nullptr, nullptr, N);
}

// Round 13
// 394.150 us; speedup vs baseline: 1.0930x; 1.0930x over previous
//
#include <hip/hip_runtime.h>
#include <hip/hip_fp16.h>
#include <cstdint>
#include <cstddef>

// ---------------------------------------------------------------------------
// GIN forward, all-fp16 intermediates, fp16 MFMA GEMMs, SINGLE fp16 W plane
// (BN re-normalizes each layer -> fp16 W error stays ~2e-3/GEMM, well under
// the 0.132 threshold):
//  L0: gather64(x_h)->pre0; gemm(64->128,+b1,+stats)->t0; gemm(128->128,BN,+b2)->h1
//  L1: gather128(h1)->pre1; gemm(128->128,+b1,+stats)->t1; gemm(128->128,BN,+b2)->h2
//  L2: gemm(128->64)->z; gather64(z,+b1)->y; stats; gemm(64->64,BN,+b2)->out f32
// GEMM: W staged in LDS (XOR-swizzled, conflict-free ds_read_b128), A hoisted;
// 17.5KB LDS -> 5 blocks/CU. CSR fill: static blockIdx&7 partition (proven 54us).
// ---------------------------------------------------------------------------

static constexpr float BN_EPS_F = 1e-5f;

typedef __attribute__((ext_vector_type(8))) _Float16 f16x8;
typedef __attribute__((ext_vector_type(4))) float f32x4;

// ------------------------- CSR build kernels -------------------------------

__global__ __launch_bounds__(1024) void scan_part_kernel(const int* __restrict__ deg,
                                                         int* __restrict__ ex,
                                                         int* __restrict__ bsum, int n) {
    __shared__ int sm[1024];
    int t = threadIdx.x;
    int g = blockIdx.x * 1024 + t;
    int v = (g < n) ? deg[g] : 0;
    sm[t] = v;
    __syncthreads();
    #pragma unroll
    for (int off = 1; off < 1024; off <<= 1) {
        int x = (t >= off) ? sm[t - off] : 0;
        __syncthreads();
        sm[t] += x;
        __syncthreads();
    }
    int incl = sm[t];
    if (g < n) ex[g] = incl - v;
    if (t == 1023) bsum[blockIdx.x] = incl;
}

__global__ __launch_bounds__(128) void scan_tops_kernel(int* __restrict__ bsum, int nb) {
    __shared__ int sm[128];
    int t = threadIdx.x;
    int v = (t < nb) ? bsum[t] : 0;
    sm[t] = v;
    __syncthreads();
    #pragma unroll
    for (int off = 1; off < 128; off <<= 1) {
        int x = (t >= off) ? sm[t - off] : 0;
        __syncthreads();
        sm[t] += x;
        __syncthreads();
    }
    if (t < nb) bsum[t] = sm[t] - v;
}

__global__ __launch_bounds__(1024) void scan_add_kernel(int* __restrict__ starts,
                                                        int* __restrict__ cursor,
                                                        const int* __restrict__ bsum,
                                                        int n, int E) {
    int g = blockIdx.x * 1024 + threadIdx.x;
    if (g < n) {
        int v = starts[g] + bsum[blockIdx.x];
        starts[g] = v;
        cursor[g] = v;
    }
    if (g == 0) starts[n] = E;
}

// Static XCD-partitioned fill (round-8/11 proven 54us; XCC/steal variants both
// regressed -> write-amp is intrinsic to scatter fill, stop chasing).

__global__ __launch_bounds__(256) void fill_part_kernel(const int* __restrict__ src,
                                                        const int* __restrict__ dst,
                                                        int* __restrict__ cursor,
                                                        int* __restrict__ srcs,
                                                        int E, int P) {
    const unsigned r = blockIdx.x & 7;
    const int chunk = blockIdx.x >> 3;
    const int nchunks = gridDim.x >> 3;
    const int cs = (E + nchunks - 1) / nchunks;
    const int lo = chunk * cs;
    const int hi = (lo + cs < E) ? lo + cs : E;
    for (int e = lo + (int)threadIdx.x; e < hi; e += 256) {
        int d = dst[e];
        unsigned part = (unsigned)d / (unsigned)P;
        if (part > 7u) part = 7u;
        if (part == r) {
            int p = atomicAdd(&cursor[d], 1);
            srcs[p] = src[e];
        }
    }
}

// ------------------------- gather: out_h = x + sum_j x[src_j] (+bias) ------
// 1 wave per node; fp16 in/out; f32 accumulate; 4-edge clamped unroll.

template <int D, bool BIAS, bool ZSUMS>
__global__ __launch_bounds__(64) void gather_hh(const __half* __restrict__ X,
                                                const int* __restrict__ starts,
                                                const int* __restrict__ srcs,
                                                const float* __restrict__ bias,
                                                __half* __restrict__ out,
                                                float* __restrict__ sums,
                                                int nsum, int n) {
    const int node = blockIdx.x;
    const int lane = threadIdx.x;
    if (ZSUMS && node == 0) {
        for (int i = lane; i < nsum; i += 64) sums[i] = 0.f;
    }
    const int s = starts[node];
    const int e = starts[node + 1];

    if (D == 64) {
        float a = __half2float(X[(size_t)node * 64 + lane]);
        for (int j = s; j < e; j += 4) {
            int i0 = srcs[j];
            int i1 = srcs[(j + 1 < e) ? j + 1 : e - 1];
            int i2 = srcs[(j + 2 < e) ? j + 2 : e - 1];
            int i3 = srcs[(j + 3 < e) ? j + 3 : e - 1];
            float v0 = __half2float(X[(size_t)i0 * 64 + lane]);
            float v1 = __half2float(X[(size_t)i1 * 64 + lane]);
            float v2 = __half2float(X[(size_t)i2 * 64 + lane]);
            float v3 = __half2float(X[(size_t)i3 * 64 + lane]);
            a += v0;
            a += (j + 1 < e) ? v1 : 0.f;
            a += (j + 2 < e) ? v2 : 0.f;
            a += (j + 3 < e) ? v3 : 0.f;
        }
        if (BIAS) a += bias[lane];
        out[(size_t)node * 64 + lane] = __float2half(a);
    } else {
        const __half2* X2 = (const __half2*)X;  // row stride 64 half2
        float2 a = __half22float2(X2[(size_t)node * 64 + lane]);
        for (int j = s; j < e; j += 4) {
            int i0 = srcs[j];
            int i1 = srcs[(j + 1 < e) ? j + 1 : e - 1];
            int i2 = srcs[(j + 2 < e) ? j + 2 : e - 1];
            int i3 = srcs[(j + 3 < e) ? j + 3 : e - 1];
            float2 v0 = __half22float2(X2[(size_t)i0 * 64 + lane]);
            float2 v1 = __half22float2(X2[(size_t)i1 * 64 + lane]);
            float2 v2 = __half22float2(X2[(size_t)i2 * 64 + lane]);
            float2 v3 = __half22float2(X2[(size_t)i3 * 64 + lane]);
            a.x += v0.x; a.y += v0.y;
            if (j + 1 < e) { a.x += v1.x; a.y += v1.y; }
            if (j + 2 < e) { a.x += v2.x; a.y += v2.y; }
            if (j + 3 < e) { a.x += v3.x; a.y += v3.y; }
        }
        __half2* O2 = (__half2*)out;
        O2[(size_t)node * 64 + lane] = __floats2half2_rn(a.x, a.y);
    }
}

// ---- weight convert (fp16, transposed) + histogram + x->fp16 (one launch) -
// cursor zeroed beforehand by hipMemsetAsync.

struct WsArgs {
    const float* w[6];
    short* hi[6];
    int K[6], Nc[6], base[6];
    int total;
    const int* dstp;
    int* deg;
    int E;
    const float* xf;
    __half* xh;
    int nx4;   // N*64/4
};

__global__ __launch_bounds__(256) void wsplit_all(WsArgs a) {
    int idx = blockIdx.x * 256 + threadIdx.x;
    int stride = gridDim.x * 256;
    for (int i = idx; i < a.E; i += stride) atomicAdd(&a.deg[a.dstp[i]], 1);
    for (int i = idx; i < a.nx4; i += stride) {
        float4 v = reinterpret_cast<const float4*>(a.xf)[i];
        ushort4 o;
        o.x = __half_as_ushort(__float2half(v.x));
        o.y = __half_as_ushort(__float2half(v.y));
        o.z = __half_as_ushort(__float2half(v.z));
        o.w = __half_as_ushort(__float2half(v.w));
        reinterpret_cast<ushort4*>(a.xh)[i] = o;
    }
    for (int i = idx; i < a.total; i += stride) {
        int s = 0;
        #pragma unroll
        for (int k = 1; k < 6; ++k)
            if (i >= a.base[k]) s = k;
        int local = i - a.base[s];
        int K = a.K[s], Nc = a.Nc[s];
        int nn = local / K, kk = local - nn * K;
        float f = a.w[s][(size_t)kk * Nc + nn];
        a.hi[s][local] = (short)__half_as_ushort(__float2half(f));
    }
}

// ------------------------- fp16 MFMA GEMM, W via LDS -----------------------
// C = [relu(BN(A))|A] @ Wh (+bias) (+stats); A fp16 [N][DI] feeds
// mfma_f32_16x16x32_f16 directly; W fp16 [DO][DI] staged in LDS with XOR
// swizzle (kelem ^= (row&7)<<3 on 8-half granules), conflict-free
// ds_read_b128. Wave: 32 rows x 64 cols; block 128 rows; LDS ~17.5KB.

template <int DI, int DO, bool BN, bool STATS, bool BIAS, bool OUTF16>
__global__ __launch_bounds__(256) void gemm16(const __half* __restrict__ A,
                                              const short* __restrict__ Wh,
                                              const float* __restrict__ bias,
                                              const float* __restrict__ sums_in,
                                              const float* __restrict__ gvec,
                                              const float* __restrict__ bevec,
                                              float inv_n,
                                              float* __restrict__ Cf,
                                              __half* __restrict__ Ch,
                                              float* __restrict__ sums_out, int nrows) {
    constexpr int CT = DO / 64;     // column tiles
    constexpr int KI = DI / 32;
    constexpr int WCH = 64 * DI / 8;  // 16B chunks in W tile
    __shared__ __align__(16) _Float16 wlds[64 * DI];
    __shared__ float s_scale[DI], s_shift[DI];
    __shared__ float ssum[64], sqsum[64];

    const int t = threadIdx.x;
    const int rowblk = blockIdx.x / CT;
    const int colbase = (blockIdx.x % CT) * 64;
    const int wave = t >> 6;
    const int lane = t & 63;
    const int lr = lane & 15;
    const int kb = lane >> 4;

    const int row_base = rowblk * 128 + wave * 32;
    const int r0 = row_base + lr;
    const int r1 = r0 + 16;
    const _Float16* a0p = (const _Float16*)A + (size_t)(r0 < nrows ? r0 : 0) * DI + kb * 8;
    const _Float16* a1p = (const _Float16*)A + (size_t)(r1 < nrows ? r1 : 0) * DI + kb * 8;

    // ---- hoisted A loads (global, overlap W staging) ----
    f16x8 a0[KI], a1[KI];
    #pragma unroll
    for (int ki = 0; ki < KI; ++ki) {
        a0[ki] = *reinterpret_cast<const f16x8*>(a0p + ki * 32);
        a1[ki] = *reinterpret_cast<const f16x8*>(a1p + ki * 32);
    }

    // ---- stage W tile into LDS, swizzled ----
    #pragma unroll
    for (int i = 0; i < WCH / 256; ++i) {
        int c = t + i * 256;
        int row = c / (DI / 8);
        int kc = c - row * (DI / 8);
        const _Float16* gsrc = (const _Float16*)Wh + (size_t)(colbase + row) * DI + kc * 8;
        f16x8 v = *reinterpret_cast<const f16x8*>(gsrc);
        int koff = (kc * 8) ^ ((row & 7) << 3);
        *reinterpret_cast<f16x8*>(&wlds[row * DI + koff]) = v;
    }

    if (BN) {
        if (t < DI) {
            float mu = sums_in[t] * inv_n;
            float var = sums_in[DI + t] * inv_n - mu * mu;
            float inv = rsqrtf(var + BN_EPS_F);
            float sc = gvec[t] * inv;
            s_scale[t] = sc;
            s_shift[t] = fmaf(-mu, sc, bevec[t]);
        }
    }
    if (STATS) {
        if (t < 64) { ssum[t] = 0.f; sqsum[t] = 0.f; }
    }
    __syncthreads();

    if (BN) {
        #pragma unroll
        for (int ki = 0; ki < KI; ++ki) {
            const int kk = ki * 32 + kb * 8;
            #pragma unroll
            for (int j = 0; j < 8; ++j) {
                float sc = s_scale[kk + j];
                float sh = s_shift[kk + j];
                a0[ki][j] = (_Float16)fmaxf(fmaf((float)a0[ki][j], sc, sh), 0.f);
                a1[ki][j] = (_Float16)fmaxf(fmaf((float)a1[ki][j], sc, sh), 0.f);
            }
        }
    }

    f32x4 acc[2][4];
    #pragma unroll
    for (int m = 0; m < 2; ++m)
        #pragma unroll
        for (int nf = 0; nf < 4; ++nf) acc[m][nf] = f32x4{0.f, 0.f, 0.f, 0.f};

    const int swz = (lr & 7) << 3;
    #pragma unroll
    for (int nf = 0; nf < 4; ++nf) {
        const int wrow = nf * 16 + lr;
        #pragma unroll
        for (int ki = 0; ki < KI; ++ki) {
            const int ke = (ki * 32 + kb * 8) ^ swz;
            f16x8 bh = *reinterpret_cast<const f16x8*>(&wlds[wrow * DI + ke]);
            acc[0][nf] = __builtin_amdgcn_mfma_f32_16x16x32_f16(a0[ki], bh, acc[0][nf], 0, 0, 0);
            acc[1][nf] = __builtin_amdgcn_mfma_f32_16x16x32_f16(a1[ki], bh, acc[1][nf], 0, 0, 0);
        }
    }

    #pragma unroll
    for (int nf = 0; nf < 4; ++nf) {
        const int lcol = nf * 16 + lr;
        const int col = colbase + lcol;
        const float b = BIAS ? bias[col] : 0.f;
        float s = 0.f, q = 0.f;
        #pragma unroll
        for (int mf = 0; mf < 2; ++mf) {
            const int rbase = row_base + mf * 16 + kb * 4;
            #pragma unroll
            for (int reg = 0; reg < 4; ++reg) {
                const int r = rbase + reg;
                const float val = acc[mf][nf][reg] + b;
                if (r < nrows) {
                    const size_t idx = (size_t)r * DO + col;
                    if (OUTF16) Ch[idx] = __float2half(val);
                    else Cf[idx] = val;
                    if (STATS) {
                        s += val;
                        q = fmaf(val, val, q);
                    }
                }
            }
        }
        if (STATS) {
            s += __shfl_xor(s, 16);
            s += __shfl_xor(s, 32);
            q += __shfl_xor(q, 16);
            q += __shfl_xor(q, 32);
            if (lane < 16) {
                atomicAdd(&ssum[lcol], s);
                atomicAdd(&sqsum[lcol], q);
            }
        }
    }
    if (STATS) {
        __syncthreads();
        if (t < 64) {
            atomicAdd(&sums_out[colbase + t], ssum[t]);
            atomicAdd(&sums_out[DO + colbase + t], sqsum[t]);
        }
    }
}

// ------------------------- BN stats over fp16 (layer 2) --------------------

template <int DO>
__global__ __launch_bounds__(256) void stats_h(const __half* __restrict__ H,
                                               float* __restrict__ sums, int nrows) {
    constexpr int G = 256 / DO;
    int t = threadIdx.x;
    int col = t % DO;
    int grp = t / DO;
    float s = 0.f, s2 = 0.f;
    for (int r = blockIdx.x * G + grp; r < nrows; r += gridDim.x * G) {
        float v = __half2float(H[(size_t)r * DO + col]);
        s += v;
        s2 = fmaf(v, v, s2);
    }
    __shared__ float sm[256], sm2[256];
    sm[t] = s;
    sm2[t] = s2;
    __syncthreads();
    if (grp == 0) {
        #pragma unroll
        for (int g = 1; g < G; ++g) {
            s += sm[g * DO + col];
            s2 += sm2[g * DO + col];
        }
        atomicAdd(&sums[col], s);
        atomicAdd(&sums[DO + col], s2);
    }
}

// ------------------------- host orchestration ------------------------------

static inline size_t align_up(size_t v, size_t a) { return (v + a - 1) & ~(a - 1); }

extern "C" void kernel_launch(void* const* d_in, const int* in_sizes, int n_in,
                              void* d_out, int out_size, void* d_ws, size_t ws_size,
                              hipStream_t stream) {
    const float* x = (const float*)d_in[0];
    const int* ei = (const int*)d_in[1];
    const int N = in_sizes[0] / 64;
    const int E = in_sizes[1] / 2;
    const int* src = ei;
    const int* dst = ei + E;

    const float* w1[3]; const float* b1[3]; const float* gg[3];
    const float* be[3]; const float* w2[3]; const float* b2[3];
    for (int l = 0; l < 3; ++l) {
        w1[l] = (const float*)d_in[2 + 6 * l + 0];
        b1[l] = (const float*)d_in[2 + 6 * l + 1];
        gg[l] = (const float*)d_in[2 + 6 * l + 2];
        be[l] = (const float*)d_in[2 + 6 * l + 3];
        w2[l] = (const float*)d_in[2 + 6 * l + 4];
        b2[l] = (const float*)d_in[2 + 6 * l + 5];
    }

    char* ws = (char*)d_ws;
    size_t off = 0;
    auto alloc = [&](size_t bytes) {
        void* p = ws + off;
        off = align_up(off + bytes, 64);
        return p;
    };
    __half* HA   = (__half*)alloc((size_t)N * 128 * 2);  // t0 / pre1 / h2
    __half* HB   = (__half*)alloc((size_t)N * 128 * 2);  // h1 / t1
    __half* XH   = (__half*)alloc((size_t)N * 64 * 2);   // x fp16, later z
    __half* PRE0 = (__half*)alloc((size_t)N * 64 * 2);   // pre0, later y
    int* srcs   = (int*)alloc((size_t)E * 4);
    int* starts = (int*)alloc((size_t)(N + 1) * 4);
    int* cursor = (int*)alloc((size_t)N * 4);
    int* bsum   = (int*)alloc(256 * 4);
    float* sums = (float*)alloc(256 * 4);

    const int wdims[6][2] = {{64,128},{128,128},{128,128},{128,128},{128,64},{64,64}};
    const float* wsrc[6] = {w1[0], w2[0], w1[1], w2[1], w1[2], w2[2]};
    short* wh[6];
    WsArgs wa;
    int base = 0;
    for (int i = 0; i < 6; ++i) {
        int elems = wdims[i][0] * wdims[i][1];
        wh[i] = (short*)alloc((size_t)elems * 2);
        wa.w[i] = wsrc[i]; wa.hi[i] = wh[i];
        wa.K[i] = wdims[i][0]; wa.Nc[i] = wdims[i][1]; wa.base[i] = base;
        base += elems;
    }
    wa.total = base;
    wa.dstp = dst;
    wa.deg = cursor;
    wa.E = E;
    wa.xf = x;
    wa.xh = XH;
    wa.nx4 = N * 16;
    (void)ws_size; (void)n_in; (void)out_size;

    const float inv_n = 1.0f / (float)N;

    // ---- zero cursor; weight convert + histogram + x->fp16 ----
    hipMemsetAsync(cursor, 0, (size_t)N * 4, stream);
    wsplit_all<<<4096, 256, 0, stream>>>(wa);

    // ---- CSR scan + fill ----
    int chunks = (N + 1023) / 1024;
    scan_part_kernel<<<chunks, 1024, 0, stream>>>(cursor, starts, bsum, N);
    scan_tops_kernel<<<1, 128, 0, stream>>>(bsum, chunks);
    scan_add_kernel<<<chunks, 1024, 0, stream>>>(starts, cursor, bsum, N, E);
    int P = N / 8;
    if (P < 1) P = 1;
    fill_part_kernel<<<1024, 256, 0, stream>>>(src, dst, cursor, srcs, E, P);

    const int nb = (N + 127) / 128;

    // ---- layer 0 ----
    gather_hh<64, false, true><<<N, 64, 0, stream>>>(
        XH, starts, srcs, nullptr, PRE0, sums, 256, N);
    gemm16<64, 128, false, true, true, true><<<nb * 2, 256, 0, stream>>>(
        PRE0, wh[0], b1[0], nullptr, nullptr, nullptr, inv_n,
        nullptr, HA, sums, N);
    gemm16<128, 128, true, false, true, true><<<nb * 2, 256, 0, stream>>>(
        HA, wh[1], b2[0], sums, gg[0], be[0], inv_n,
        nullptr, HB, nullptr, N);

    // ---- layer 1 ----
    gather_hh<128, false, true><<<N, 64, 0, stream>>>(
        HB, starts, srcs, nullptr, HA, sums, 256, N);
    gemm16<128, 128, false, true, true, true><<<nb * 2, 256, 0, stream>>>(
        HA, wh[2], b1[1], nullptr, nullptr, nullptr, inv_n,
        nullptr, HB, sums, N);
    gemm16<128, 128, true, false, true, true><<<nb * 2, 256, 0, stream>>>(
        HB, wh[3], b2[1], sums, gg[1], be[1], inv_n,
        nullptr, HA, nullptr, N);

    // ---- layer 2 (aggregation commuted through W1) ----
    gemm16<128, 64, false, false, false, true><<<nb, 256, 0, stream>>>(
        HA, wh[4], nullptr, nullptr, nullptr, nullptr, inv_n,
        nullptr, XH, nullptr, N);
    gather_hh<64, true, true><<<N, 64, 0, stream>>>(
        XH, starts, srcs, b1[2], PRE0, sums, 128, N);
    stats_h<64><<<512, 256, 0, stream>>>(PRE0, sums, N);
    gemm16<64, 64, true, false, true, false><<<nb, 256, 0, stream>>>(
        PRE0, wh[5], b2[2], sums, gg[2], be[2], inv_n,
        (float*)d_out, nullptr, nullptr, N);
}

// Round 14
// 392.692 us; speedup vs baseline: 1.0970x; 1.0037x over previous
//
#include <hip/hip_runtime.h>
#include <hip/hip_fp16.h>
#include <cstdint>
#include <cstddef>

// ---------------------------------------------------------------------------
// GIN forward, all-fp16 intermediates, fp16 MFMA GEMMs, single fp16 W plane:
//  L0: gather64(x_h)->pre0; gemm(64->128,+b1,+stats)->t0; gemm(128->128,BN,+b2)->h1
//  L1: gather128(h1)->pre1; gemm(128->128,+b1,+stats)->t1; gemm(128->128,BN,+b2)->h2
//  L2: gemm(128->64)->z; gather64(z,+b1)->y; stats; gemm(64->64,BN,+b2)->out f32
// GEMM: W staged in LDS (XOR-swizzled, conflict-free ds_read_b128), A hoisted.
// Gather: 1 wave/node, 8-edge clamped in-flight unroll (2 rounds at deg~10).
// CSR fill: static blockIdx&7 partition (proven 54us floor).
// ---------------------------------------------------------------------------

static constexpr float BN_EPS_F = 1e-5f;

typedef __attribute__((ext_vector_type(8))) _Float16 f16x8;
typedef __attribute__((ext_vector_type(4))) float f32x4;

// ------------------------- CSR build kernels -------------------------------

__global__ __launch_bounds__(1024) void scan_part_kernel(const int* __restrict__ deg,
                                                         int* __restrict__ ex,
                                                         int* __restrict__ bsum, int n) {
    __shared__ int sm[1024];
    int t = threadIdx.x;
    int g = blockIdx.x * 1024 + t;
    int v = (g < n) ? deg[g] : 0;
    sm[t] = v;
    __syncthreads();
    #pragma unroll
    for (int off = 1; off < 1024; off <<= 1) {
        int x = (t >= off) ? sm[t - off] : 0;
        __syncthreads();
        sm[t] += x;
        __syncthreads();
    }
    int incl = sm[t];
    if (g < n) ex[g] = incl - v;
    if (t == 1023) bsum[blockIdx.x] = incl;
}

__global__ __launch_bounds__(128) void scan_tops_kernel(int* __restrict__ bsum, int nb) {
    __shared__ int sm[128];
    int t = threadIdx.x;
    int v = (t < nb) ? bsum[t] : 0;
    sm[t] = v;
    __syncthreads();
    #pragma unroll
    for (int off = 1; off < 128; off <<= 1) {
        int x = (t >= off) ? sm[t - off] : 0;
        __syncthreads();
        sm[t] += x;
        __syncthreads();
    }
    if (t < nb) bsum[t] = sm[t] - v;
}

__global__ __launch_bounds__(1024) void scan_add_kernel(int* __restrict__ starts,
                                                        int* __restrict__ cursor,
                                                        const int* __restrict__ bsum,
                                                        int n, int E) {
    int g = blockIdx.x * 1024 + threadIdx.x;
    if (g < n) {
        int v = starts[g] + bsum[blockIdx.x];
        starts[g] = v;
        cursor[g] = v;
    }
    if (g == 0) starts[n] = E;
}

// Static XCD-partitioned fill (proven 54us; XCC/steal variants regressed ->
// write-amp is intrinsic to scatter fill, stop chasing).

__global__ __launch_bounds__(256) void fill_part_kernel(const int* __restrict__ src,
                                                        const int* __restrict__ dst,
                                                        int* __restrict__ cursor,
                                                        int* __restrict__ srcs,
                                                        int E, int P) {
    const unsigned r = blockIdx.x & 7;
    const int chunk = blockIdx.x >> 3;
    const int nchunks = gridDim.x >> 3;
    const int cs = (E + nchunks - 1) / nchunks;
    const int lo = chunk * cs;
    const int hi = (lo + cs < E) ? lo + cs : E;
    for (int e = lo + (int)threadIdx.x; e < hi; e += 256) {
        int d = dst[e];
        unsigned part = (unsigned)d / (unsigned)P;
        if (part > 7u) part = 7u;
        if (part == r) {
            int p = atomicAdd(&cursor[d], 1);
            srcs[p] = src[e];
        }
    }
}

// ------------------------- gather: out_h = x + sum_j x[src_j] (+bias) ------
// 1 wave per node; fp16 in/out; f32 accumulate; 8-edge clamped in-flight
// unroll (all 8 loads independent & unconditional -> 8 outstanding VMEM ops).

template <int D, bool BIAS, bool ZSUMS>
__global__ __launch_bounds__(64) void gather_hh(const __half* __restrict__ X,
                                                const int* __restrict__ starts,
                                                const int* __restrict__ srcs,
                                                const float* __restrict__ bias,
                                                __half* __restrict__ out,
                                                float* __restrict__ sums,
                                                int nsum, int n) {
    const int node = blockIdx.x;
    const int lane = threadIdx.x;
    if (ZSUMS && node == 0) {
        for (int i = lane; i < nsum; i += 64) sums[i] = 0.f;
    }
    const int s = starts[node];
    const int e = starts[node + 1];

    if (D == 64) {
        float a = __half2float(X[(size_t)node * 64 + lane]);
        for (int j = s; j < e; j += 8) {
            int idx[8];
            #pragma unroll
            for (int u = 0; u < 8; ++u)
                idx[u] = srcs[(j + u < e) ? j + u : e - 1];
            float v[8];
            #pragma unroll
            for (int u = 0; u < 8; ++u)
                v[u] = __half2float(X[(size_t)idx[u] * 64 + lane]);
            a += v[0];
            #pragma unroll
            for (int u = 1; u < 8; ++u)
                a += (j + u < e) ? v[u] : 0.f;
        }
        if (BIAS) a += bias[lane];
        out[(size_t)node * 64 + lane] = __float2half(a);
    } else {
        const __half2* X2 = (const __half2*)X;  // row stride 64 half2
        float2 a = __half22float2(X2[(size_t)node * 64 + lane]);
        for (int j = s; j < e; j += 8) {
            int idx[8];
            #pragma unroll
            for (int u = 0; u < 8; ++u)
                idx[u] = srcs[(j + u < e) ? j + u : e - 1];
            float2 v[8];
            #pragma unroll
            for (int u = 0; u < 8; ++u)
                v[u] = __half22float2(X2[(size_t)idx[u] * 64 + lane]);
            a.x += v[0].x; a.y += v[0].y;
            #pragma unroll
            for (int u = 1; u < 8; ++u) {
                if (j + u < e) { a.x += v[u].x; a.y += v[u].y; }
            }
        }
        __half2* O2 = (__half2*)out;
        O2[(size_t)node * 64 + lane] = __floats2half2_rn(a.x, a.y);
    }
}

// ---- weight convert (fp16, transposed) + histogram + x->fp16 (one launch) -
// cursor zeroed beforehand by hipMemsetAsync.

struct WsArgs {
    const float* w[6];
    short* hi[6];
    int K[6], Nc[6], base[6];
    int total;
    const int* dstp;
    int* deg;
    int E;
    const float* xf;
    __half* xh;
    int nx4;   // N*64/4
};

__global__ __launch_bounds__(256) void wsplit_all(WsArgs a) {
    int idx = blockIdx.x * 256 + threadIdx.x;
    int stride = gridDim.x * 256;
    for (int i = idx; i < a.E; i += stride) atomicAdd(&a.deg[a.dstp[i]], 1);
    for (int i = idx; i < a.nx4; i += stride) {
        float4 v = reinterpret_cast<const float4*>(a.xf)[i];
        ushort4 o;
        o.x = __half_as_ushort(__float2half(v.x));
        o.y = __half_as_ushort(__float2half(v.y));
        o.z = __half_as_ushort(__float2half(v.z));
        o.w = __half_as_ushort(__float2half(v.w));
        reinterpret_cast<ushort4*>(a.xh)[i] = o;
    }
    for (int i = idx; i < a.total; i += stride) {
        int s = 0;
        #pragma unroll
        for (int k = 1; k < 6; ++k)
            if (i >= a.base[k]) s = k;
        int local = i - a.base[s];
        int K = a.K[s], Nc = a.Nc[s];
        int nn = local / K, kk = local - nn * K;
        float f = a.w[s][(size_t)kk * Nc + nn];
        a.hi[s][local] = (short)__half_as_ushort(__float2half(f));
    }
}

// ------------------------- fp16 MFMA GEMM, W via LDS -----------------------
// C = [relu(BN(A))|A] @ Wh (+bias) (+stats); A fp16 [N][DI] feeds
// mfma_f32_16x16x32_f16 directly; W fp16 [DO][DI] staged in LDS with XOR
// swizzle (kelem ^= (row&7)<<3 on 8-half granules), conflict-free
// ds_read_b128. Wave: 32 rows x 64 cols; block 128 rows; LDS ~17.5KB.

template <int DI, int DO, bool BN, bool STATS, bool BIAS, bool OUTF16>
__global__ __launch_bounds__(256) void gemm16(const __half* __restrict__ A,
                                              const short* __restrict__ Wh,
                                              const float* __restrict__ bias,
                                              const float* __restrict__ sums_in,
                                              const float* __restrict__ gvec,
                                              const float* __restrict__ bevec,
                                              float inv_n,
                                              float* __restrict__ Cf,
                                              __half* __restrict__ Ch,
                                              float* __restrict__ sums_out, int nrows) {
    constexpr int CT = DO / 64;     // column tiles
    constexpr int KI = DI / 32;
    constexpr int WCH = 64 * DI / 8;  // 16B chunks in W tile
    __shared__ __align__(16) _Float16 wlds[64 * DI];
    __shared__ float s_scale[DI], s_shift[DI];
    __shared__ float ssum[64], sqsum[64];

    const int t = threadIdx.x;
    const int rowblk = blockIdx.x / CT;
    const int colbase = (blockIdx.x % CT) * 64;
    const int wave = t >> 6;
    const int lane = t & 63;
    const int lr = lane & 15;
    const int kb = lane >> 4;

    const int row_base = rowblk * 128 + wave * 32;
    const int r0 = row_base + lr;
    const int r1 = r0 + 16;
    const _Float16* a0p = (const _Float16*)A + (size_t)(r0 < nrows ? r0 : 0) * DI + kb * 8;
    const _Float16* a1p = (const _Float16*)A + (size_t)(r1 < nrows ? r1 : 0) * DI + kb * 8;

    // ---- hoisted A loads (global, overlap W staging) ----
    f16x8 a0[KI], a1[KI];
    #pragma unroll
    for (int ki = 0; ki < KI; ++ki) {
        a0[ki] = *reinterpret_cast<const f16x8*>(a0p + ki * 32);
        a1[ki] = *reinterpret_cast<const f16x8*>(a1p + ki * 32);
    }

    // ---- stage W tile into LDS, swizzled ----
    #pragma unroll
    for (int i = 0; i < WCH / 256; ++i) {
        int c = t + i * 256;
        int row = c / (DI / 8);
        int kc = c - row * (DI / 8);
        const _Float16* gsrc = (const _Float16*)Wh + (size_t)(colbase + row) * DI + kc * 8;
        f16x8 v = *reinterpret_cast<const f16x8*>(gsrc);
        int koff = (kc * 8) ^ ((row & 7) << 3);
        *reinterpret_cast<f16x8*>(&wlds[row * DI + koff]) = v;
    }

    if (BN) {
        if (t < DI) {
            float mu = sums_in[t] * inv_n;
            float var = sums_in[DI + t] * inv_n - mu * mu;
            float inv = rsqrtf(var + BN_EPS_F);
            float sc = gvec[t] * inv;
            s_scale[t] = sc;
            s_shift[t] = fmaf(-mu, sc, bevec[t]);
        }
    }
    if (STATS) {
        if (t < 64) { ssum[t] = 0.f; sqsum[t] = 0.f; }
    }
    __syncthreads();

    if (BN) {
        #pragma unroll
        for (int ki = 0; ki < KI; ++ki) {
            const int kk = ki * 32 + kb * 8;
            #pragma unroll
            for (int j = 0; j < 8; ++j) {
                float sc = s_scale[kk + j];
                float sh = s_shift[kk + j];
                a0[ki][j] = (_Float16)fmaxf(fmaf((float)a0[ki][j], sc, sh), 0.f);
                a1[ki][j] = (_Float16)fmaxf(fmaf((float)a1[ki][j], sc, sh), 0.f);
            }
        }
    }

    f32x4 acc[2][4];
    #pragma unroll
    for (int m = 0; m < 2; ++m)
        #pragma unroll
        for (int nf = 0; nf < 4; ++nf) acc[m][nf] = f32x4{0.f, 0.f, 0.f, 0.f};

    const int swz = (lr & 7) << 3;
    #pragma unroll
    for (int nf = 0; nf < 4; ++nf) {
        const int wrow = nf * 16 + lr;
        #pragma unroll
        for (int ki = 0; ki < KI; ++ki) {
            const int ke = (ki * 32 + kb * 8) ^ swz;
            f16x8 bh = *reinterpret_cast<const f16x8*>(&wlds[wrow * DI + ke]);
            acc[0][nf] = __builtin_amdgcn_mfma_f32_16x16x32_f16(a0[ki], bh, acc[0][nf], 0, 0, 0);
            acc[1][nf] = __builtin_amdgcn_mfma_f32_16x16x32_f16(a1[ki], bh, acc[1][nf], 0, 0, 0);
        }
    }

    #pragma unroll
    for (int nf = 0; nf < 4; ++nf) {
        const int lcol = nf * 16 + lr;
        const int col = colbase + lcol;
        const float b = BIAS ? bias[col] : 0.f;
        float s = 0.f, q = 0.f;
        #pragma unroll
        for (int mf = 0; mf < 2; ++mf) {
            const int rbase = row_base + mf * 16 + kb * 4;
            #pragma unroll
            for (int reg = 0; reg < 4; ++reg) {
                const int r = rbase + reg;
                const float val = acc[mf][nf][reg] + b;
                if (r < nrows) {
                    const size_t idx = (size_t)r * DO + col;
                    if (OUTF16) Ch[idx] = __float2half(val);
                    else Cf[idx] = val;
                    if (STATS) {
                        s += val;
                        q = fmaf(val, val, q);
                    }
                }
            }
        }
        if (STATS) {
            s += __shfl_xor(s, 16);
            s += __shfl_xor(s, 32);
            q += __shfl_xor(q, 16);
            q += __shfl_xor(q, 32);
            if (lane < 16) {
                atomicAdd(&ssum[lcol], s);
                atomicAdd(&sqsum[lcol], q);
            }
        }
    }
    if (STATS) {
        __syncthreads();
        if (t < 64) {
            atomicAdd(&sums_out[colbase + t], ssum[t]);
            atomicAdd(&sums_out[DO + colbase + t], sqsum[t]);
        }
    }
}

// ------------------------- BN stats over fp16 (layer 2) --------------------

template <int DO>
__global__ __launch_bounds__(256) void stats_h(const __half* __restrict__ H,
                                               float* __restrict__ sums, int nrows) {
    constexpr int G = 256 / DO;
    int t = threadIdx.x;
    int col = t % DO;
    int grp = t / DO;
    float s = 0.f, s2 = 0.f;
    for (int r = blockIdx.x * G + grp; r < nrows; r += gridDim.x * G) {
        float v = __half2float(H[(size_t)r * DO + col]);
        s += v;
        s2 = fmaf(v, v, s2);
    }
    __shared__ float sm[256], sm2[256];
    sm[t] = s;
    sm2[t] = s2;
    __syncthreads();
    if (grp == 0) {
        #pragma unroll
        for (int g = 1; g < G; ++g) {
            s += sm[g * DO + col];
            s2 += sm2[g * DO + col];
        }
        atomicAdd(&sums[col], s);
        atomicAdd(&sums[DO + col], s2);
    }
}

// ------------------------- host orchestration ------------------------------

static inline size_t align_up(size_t v, size_t a) { return (v + a - 1) & ~(a - 1); }

extern "C" void kernel_launch(void* const* d_in, const int* in_sizes, int n_in,
                              void* d_out, int out_size, void* d_ws, size_t ws_size,
                              hipStream_t stream) {
    const float* x = (const float*)d_in[0];
    const int* ei = (const int*)d_in[1];
    const int N = in_sizes[0] / 64;
    const int E = in_sizes[1] / 2;
    const int* src = ei;
    const int* dst = ei + E;

    const float* w1[3]; const float* b1[3]; const float* gg[3];
    const float* be[3]; const float* w2[3]; const float* b2[3];
    for (int l = 0; l < 3; ++l) {
        w1[l] = (const float*)d_in[2 + 6 * l + 0];
        b1[l] = (const float*)d_in[2 + 6 * l + 1];
        gg[l] = (const float*)d_in[2 + 6 * l + 2];
        be[l] = (const float*)d_in[2 + 6 * l + 3];
        w2[l] = (const float*)d_in[2 + 6 * l + 4];
        b2[l] = (const float*)d_in[2 + 6 * l + 5];
    }

    char* ws = (char*)d_ws;
    size_t off = 0;
    auto alloc = [&](size_t bytes) {
        void* p = ws + off;
        off = align_up(off + bytes, 64);
        return p;
    };
    __half* HA   = (__half*)alloc((size_t)N * 128 * 2);  // t0 / pre1 / h2
    __half* HB   = (__half*)alloc((size_t)N * 128 * 2);  // h1 / t1
    __half* XH   = (__half*)alloc((size_t)N * 64 * 2);   // x fp16, later z
    __half* PRE0 = (__half*)alloc((size_t)N * 64 * 2);   // pre0, later y
    int* srcs   = (int*)alloc((size_t)E * 4);
    int* starts = (int*)alloc((size_t)(N + 1) * 4);
    int* cursor = (int*)alloc((size_t)N * 4);
    int* bsum   = (int*)alloc(256 * 4);
    float* sums = (float*)alloc(256 * 4);

    const int wdims[6][2] = {{64,128},{128,128},{128,128},{128,128},{128,64},{64,64}};
    const float* wsrc[6] = {w1[0], w2[0], w1[1], w2[1], w1[2], w2[2]};
    short* wh[6];
    WsArgs wa;
    int base = 0;
    for (int i = 0; i < 6; ++i) {
        int elems = wdims[i][0] * wdims[i][1];
        wh[i] = (short*)alloc((size_t)elems * 2);
        wa.w[i] = wsrc[i]; wa.hi[i] = wh[i];
        wa.K[i] = wdims[i][0]; wa.Nc[i] = wdims[i][1]; wa.base[i] = base;
        base += elems;
    }
    wa.total = base;
    wa.dstp = dst;
    wa.deg = cursor;
    wa.E = E;
    wa.xf = x;
    wa.xh = XH;
    wa.nx4 = N * 16;
    (void)ws_size; (void)n_in; (void)out_size;

    const float inv_n = 1.0f / (float)N;

    // ---- zero cursor; weight convert + histogram + x->fp16 ----
    hipMemsetAsync(cursor, 0, (size_t)N * 4, stream);
    wsplit_all<<<4096, 256, 0, stream>>>(wa);

    // ---- CSR scan + fill ----
    int chunks = (N + 1023) / 1024;
    scan_part_kernel<<<chunks, 1024, 0, stream>>>(cursor, starts, bsum, N);
    scan_tops_kernel<<<1, 128, 0, stream>>>(bsum, chunks);
    scan_add_kernel<<<chunks, 1024, 0, stream>>>(starts, cursor, bsum, N, E);
    int P = N / 8;
    if (P < 1) P = 1;
    fill_part_kernel<<<1024, 256, 0, stream>>>(src, dst, cursor, srcs, E, P);

    const int nb = (N + 127) / 128;

    // ---- layer 0 ----
    gather_hh<64, false, true><<<N, 64, 0, stream>>>(
        XH, starts, srcs, nullptr, PRE0, sums, 256, N);
    gemm16<64, 128, false, true, true, true><<<nb * 2, 256, 0, stream>>>(
        PRE0, wh[0], b1[0], nullptr, nullptr, nullptr, inv_n,
        nullptr, HA, sums, N);
    gemm16<128, 128, true, false, true, true><<<nb * 2, 256, 0, stream>>>(
        HA, wh[1], b2[0], sums, gg[0], be[0], inv_n,
        nullptr, HB, nullptr, N);

    // ---- layer 1 ----
    gather_hh<128, false, true><<<N, 64, 0, stream>>>(
        HB, starts, srcs, nullptr, HA, sums, 256, N);
    gemm16<128, 128, false, true, true, true><<<nb * 2, 256, 0, stream>>>(
        HA, wh[2], b1[1], nullptr, nullptr, nullptr, inv_n,
        nullptr, HB, sums, N);
    gemm16<128, 128, true, false, true, true><<<nb * 2, 256, 0, stream>>>(
        HB, wh[3], b2[1], sums, gg[1], be[1], inv_n,
        nullptr, HA, nullptr, N);

    // ---- layer 2 (aggregation commuted through W1) ----
    gemm16<128, 64, false, false, false, true><<<nb, 256, 0, stream>>>(
        HA, wh[4], nullptr, nullptr, nullptr, nullptr, inv_n,
        nullptr, XH, nullptr, N);
    gather_hh<64, true, true><<<N, 64, 0, stream>>>(
        XH, starts, srcs, b1[2], PRE0, sums, 128, N);
    stats_h<64><<<512, 256, 0, stream>>>(PRE0, sums, N);
    gemm16<64, 64, true, false, true, false><<<nb, 256, 0, stream>>>(
        PRE0, wh[5], b2[2], sums, gg[2], be[2], inv_n,
        (float*)d_out, nullptr, nullptr, N);
}

// Round 15
// 367.396 us; speedup vs baseline: 1.1726x; 1.0689x over previous
//
#include <hip/hip_runtime.h>
#include <hip/hip_fp16.h>
#include <cstdint>
#include <cstddef>

// ---------------------------------------------------------------------------
// GIN forward, all-fp16 intermediates, fp16 MFMA GEMMs, single fp16 W plane:
//  L0: gather64(x_h)->pre0; gemm(64->128,+b1,+stats)->t0; gemm(128->128,BN,+b2)->h1
//  L1: gather128(h1)->pre1; gemm(128->128,+b1,+stats)->t1; gemm(128->128,BN,+b2)->h2
//  L2: gemm(128->64)->z; gather64(z,+b1)->y; stats; gemm(64->64,BN,+b2)->out f32
// GEMM: CT=1 (block = 128 rows x full DO; A fetched ONCE), W staged in LDS
// (XOR-swizzled, conflict-free ds_read_b128), fp16 C staged through LDS and
// dumped with coalesced f16x8 stores (kills the 2x write amplification).
// ---------------------------------------------------------------------------

static constexpr float BN_EPS_F = 1e-5f;

typedef __attribute__((ext_vector_type(8))) _Float16 f16x8;
typedef __attribute__((ext_vector_type(4))) float f32x4;

// ------------------------- CSR build kernels -------------------------------

__global__ __launch_bounds__(1024) void scan_part_kernel(const int* __restrict__ deg,
                                                         int* __restrict__ ex,
                                                         int* __restrict__ bsum, int n) {
    __shared__ int sm[1024];
    int t = threadIdx.x;
    int g = blockIdx.x * 1024 + t;
    int v = (g < n) ? deg[g] : 0;
    sm[t] = v;
    __syncthreads();
    #pragma unroll
    for (int off = 1; off < 1024; off <<= 1) {
        int x = (t >= off) ? sm[t - off] : 0;
        __syncthreads();
        sm[t] += x;
        __syncthreads();
    }
    int incl = sm[t];
    if (g < n) ex[g] = incl - v;
    if (t == 1023) bsum[blockIdx.x] = incl;
}

// scan_add with inlined top-level scan: each block reduces bsum[0..bid) itself.
__global__ __launch_bounds__(1024) void scan_add_kernel(int* __restrict__ starts,
                                                        int* __restrict__ cursor,
                                                        const int* __restrict__ bsum,
                                                        int n, int E, int nb) {
    __shared__ int red[128];
    __shared__ int s_base;
    int t = threadIdx.x;
    if (t < 128) red[t] = (t < (int)blockIdx.x && t < nb) ? bsum[t] : 0;
    __syncthreads();
    if (t < 64) {
        int v = red[t] + red[t + 64];
        #pragma unroll
        for (int off = 32; off > 0; off >>= 1) v += __shfl_down(v, off);
        if (t == 0) s_base = v;
    }
    __syncthreads();
    int base = s_base;
    int g = blockIdx.x * 1024 + t;
    if (g < n) {
        int v = starts[g] + base;
        starts[g] = v;
        cursor[g] = v;
    }
    if (g == 0) starts[n] = E;
}

// Static XCD-partitioned fill (proven 54us floor; XCC/steal variants regressed
// -> write-amp is intrinsic to scatter fill, stop chasing).

__global__ __launch_bounds__(256) void fill_part_kernel(const int* __restrict__ src,
                                                        const int* __restrict__ dst,
                                                        int* __restrict__ cursor,
                                                        int* __restrict__ srcs,
                                                        int E, int P) {
    const unsigned r = blockIdx.x & 7;
    const int chunk = blockIdx.x >> 3;
    const int nchunks = gridDim.x >> 3;
    const int cs = (E + nchunks - 1) / nchunks;
    const int lo = chunk * cs;
    const int hi = (lo + cs < E) ? lo + cs : E;
    for (int e = lo + (int)threadIdx.x; e < hi; e += 256) {
        int d = dst[e];
        unsigned part = (unsigned)d / (unsigned)P;
        if (part > 7u) part = 7u;
        if (part == r) {
            int p = atomicAdd(&cursor[d], 1);
            srcs[p] = src[e];
        }
    }
}

// ------------------------- gather: out_h = x + sum_j x[src_j] (+bias) ------
// 1 wave per node; fp16 in/out; f32 accumulate; 8-edge clamped in-flight unroll.

template <int D, bool BIAS, bool ZSUMS>
__global__ __launch_bounds__(64) void gather_hh(const __half* __restrict__ X,
                                                const int* __restrict__ starts,
                                                const int* __restrict__ srcs,
                                                const float* __restrict__ bias,
                                                __half* __restrict__ out,
                                                float* __restrict__ sums,
                                                int nsum, int n) {
    const int node = blockIdx.x;
    const int lane = threadIdx.x;
    if (ZSUMS && node == 0) {
        for (int i = lane; i < nsum; i += 64) sums[i] = 0.f;
    }
    const int s = starts[node];
    const int e = starts[node + 1];

    if (D == 64) {
        float a = __half2float(X[(size_t)node * 64 + lane]);
        for (int j = s; j < e; j += 8) {
            int idx[8];
            #pragma unroll
            for (int u = 0; u < 8; ++u)
                idx[u] = srcs[(j + u < e) ? j + u : e - 1];
            float v[8];
            #pragma unroll
            for (int u = 0; u < 8; ++u)
                v[u] = __half2float(X[(size_t)idx[u] * 64 + lane]);
            a += v[0];
            #pragma unroll
            for (int u = 1; u < 8; ++u)
                a += (j + u < e) ? v[u] : 0.f;
        }
        if (BIAS) a += bias[lane];
        out[(size_t)node * 64 + lane] = __float2half(a);
    } else {
        const __half2* X2 = (const __half2*)X;  // row stride 64 half2
        float2 a = __half22float2(X2[(size_t)node * 64 + lane]);
        for (int j = s; j < e; j += 8) {
            int idx[8];
            #pragma unroll
            for (int u = 0; u < 8; ++u)
                idx[u] = srcs[(j + u < e) ? j + u : e - 1];
            float2 v[8];
            #pragma unroll
            for (int u = 0; u < 8; ++u)
                v[u] = __half22float2(X2[(size_t)idx[u] * 64 + lane]);
            a.x += v[0].x; a.y += v[0].y;
            #pragma unroll
            for (int u = 1; u < 8; ++u) {
                if (j + u < e) { a.x += v[u].x; a.y += v[u].y; }
            }
        }
        __half2* O2 = (__half2*)out;
        O2[(size_t)node * 64 + lane] = __floats2half2_rn(a.x, a.y);
    }
}

// ---- weight convert (fp16, transposed) + histogram + x->fp16 (one launch) -
// cursor zeroed beforehand by hipMemsetAsync.

struct WsArgs {
    const float* w[6];
    short* hi[6];
    int K[6], Nc[6], base[6];
    int total;
    const int* dstp;
    int* deg;
    int E;
    const float* xf;
    __half* xh;
    int nx4;   // N*64/4
};

__global__ __launch_bounds__(256) void wsplit_all(WsArgs a) {
    int idx = blockIdx.x * 256 + threadIdx.x;
    int stride = gridDim.x * 256;
    for (int i = idx; i < a.E; i += stride) atomicAdd(&a.deg[a.dstp[i]], 1);
    for (int i = idx; i < a.nx4; i += stride) {
        float4 v = reinterpret_cast<const float4*>(a.xf)[i];
        ushort4 o;
        o.x = __half_as_ushort(__float2half(v.x));
        o.y = __half_as_ushort(__float2half(v.y));
        o.z = __half_as_ushort(__float2half(v.z));
        o.w = __half_as_ushort(__float2half(v.w));
        reinterpret_cast<ushort4*>(a.xh)[i] = o;
    }
    for (int i = idx; i < a.total; i += stride) {
        int s = 0;
        #pragma unroll
        for (int k = 1; k < 6; ++k)
            if (i >= a.base[k]) s = k;
        int local = i - a.base[s];
        int K = a.K[s], Nc = a.Nc[s];
        int nn = local / K, kk = local - nn * K;
        float f = a.w[s][(size_t)kk * Nc + nn];
        a.hi[s][local] = (short)__half_as_ushort(__float2half(f));
    }
}

// ------------------------- fp16 MFMA GEMM, CT=1, W+C via LDS ---------------
// C = [relu(BN(A))|A] @ Wh (+bias) (+stats); A fp16 [N][DI] feeds
// mfma_f32_16x16x32_f16; W fp16 [DO][DI] staged in LDS (XOR swizzle,
// conflict-free ds_read_b128); fp16 C staged in LDS then dumped coalesced.
// Block = 128 rows x DO cols (A fetched once); wave = 32 rows x DO cols.

template <int DI, int DO, bool BN, bool STATS, bool BIAS, bool OUTF16>
__global__ __launch_bounds__(256) void gemm16(const __half* __restrict__ A,
                                              const short* __restrict__ Wh,
                                              const float* __restrict__ bias,
                                              const float* __restrict__ sums_in,
                                              const float* __restrict__ gvec,
                                              const float* __restrict__ bevec,
                                              float inv_n,
                                              float* __restrict__ Cf,
                                              __half* __restrict__ Ch,
                                              float* __restrict__ sums_out, int nrows) {
    constexpr int NF = DO / 16;
    constexpr int KI = DI / 32;
    constexpr int LDSH = DO * (DI > 128 ? DI : 128);  // W tile; reused for C tile
    __shared__ __align__(16) _Float16 wlds[LDSH];
    __shared__ float s_scale[DI], s_shift[DI];
    __shared__ float ssum[DO], sqsum[DO];

    const int t = threadIdx.x;
    const int rowblk = blockIdx.x;
    const int wave = t >> 6;
    const int lane = t & 63;
    const int lr = lane & 15;
    const int kb = lane >> 4;

    const int row_base = rowblk * 128 + wave * 32;
    const int r0 = row_base + lr;
    const int r1 = r0 + 16;
    const _Float16* a0p = (const _Float16*)A + (size_t)(r0 < nrows ? r0 : 0) * DI + kb * 8;
    const _Float16* a1p = (const _Float16*)A + (size_t)(r1 < nrows ? r1 : 0) * DI + kb * 8;

    // ---- hoisted A loads (global, overlap W staging) ----
    f16x8 a0[KI], a1[KI];
    #pragma unroll
    for (int ki = 0; ki < KI; ++ki) {
        a0[ki] = *reinterpret_cast<const f16x8*>(a0p + ki * 32);
        a1[ki] = *reinterpret_cast<const f16x8*>(a1p + ki * 32);
    }

    // ---- stage W tile (full DO rows) into LDS, swizzled ----
    constexpr int WCH = DO * DI / 8;
    #pragma unroll
    for (int i = 0; i < WCH / 256; ++i) {
        int c = t + i * 256;
        int row = c / (DI / 8);
        int kc = c - row * (DI / 8);
        f16x8 v = *reinterpret_cast<const f16x8*>(
            (const _Float16*)Wh + (size_t)row * DI + kc * 8);
        int koff = (kc * 8) ^ ((row & 7) << 3);
        *reinterpret_cast<f16x8*>(&wlds[row * DI + koff]) = v;
    }

    if (BN) {
        if (t < DI) {
            float mu = sums_in[t] * inv_n;
            float var = sums_in[DI + t] * inv_n - mu * mu;
            float inv = rsqrtf(var + BN_EPS_F);
            float sc = gvec[t] * inv;
            s_scale[t] = sc;
            s_shift[t] = fmaf(-mu, sc, bevec[t]);
        }
    }
    if (STATS) {
        if (t < DO) { ssum[t] = 0.f; sqsum[t] = 0.f; }
    }
    __syncthreads();

    if (BN) {
        #pragma unroll
        for (int ki = 0; ki < KI; ++ki) {
            const int kk = ki * 32 + kb * 8;
            #pragma unroll
            for (int j = 0; j < 8; ++j) {
                float sc = s_scale[kk + j];
                float sh = s_shift[kk + j];
                a0[ki][j] = (_Float16)fmaxf(fmaf((float)a0[ki][j], sc, sh), 0.f);
                a1[ki][j] = (_Float16)fmaxf(fmaf((float)a1[ki][j], sc, sh), 0.f);
            }
        }
    }

    f32x4 acc[2][NF];
    #pragma unroll
    for (int m = 0; m < 2; ++m)
        #pragma unroll
        for (int nf = 0; nf < NF; ++nf) acc[m][nf] = f32x4{0.f, 0.f, 0.f, 0.f};

    const int swz = (lr & 7) << 3;
    #pragma unroll
    for (int nf = 0; nf < NF; ++nf) {
        const int wrow = nf * 16 + lr;
        #pragma unroll
        for (int ki = 0; ki < KI; ++ki) {
            const int ke = (ki * 32 + kb * 8) ^ swz;
            f16x8 bh = *reinterpret_cast<const f16x8*>(&wlds[wrow * DI + ke]);
            acc[0][nf] = __builtin_amdgcn_mfma_f32_16x16x32_f16(a0[ki], bh, acc[0][nf], 0, 0, 0);
            acc[1][nf] = __builtin_amdgcn_mfma_f32_16x16x32_f16(a1[ki], bh, acc[1][nf], 0, 0, 0);
        }
    }

    // ---- stats (from acc) + f32 direct writes ----
    #pragma unroll
    for (int nf = 0; nf < NF; ++nf) {
        const int col = nf * 16 + lr;
        const float b = BIAS ? bias[col] : 0.f;
        if (STATS) {
            float s = 0.f, q = 0.f;
            #pragma unroll
            for (int mf = 0; mf < 2; ++mf) {
                const int rbase = row_base + mf * 16 + kb * 4;
                #pragma unroll
                for (int reg = 0; reg < 4; ++reg) {
                    if (rbase + reg < nrows) {
                        const float val = acc[mf][nf][reg] + b;
                        s += val;
                        q = fmaf(val, val, q);
                    }
                }
            }
            s += __shfl_xor(s, 16);
            s += __shfl_xor(s, 32);
            q += __shfl_xor(q, 16);
            q += __shfl_xor(q, 32);
            if (lane < 16) {
                atomicAdd(&ssum[col], s);
                atomicAdd(&sqsum[col], q);
            }
        }
        if (!OUTF16) {
            #pragma unroll
            for (int mf = 0; mf < 2; ++mf) {
                const int rbase = row_base + mf * 16 + kb * 4;
                #pragma unroll
                for (int reg = 0; reg < 4; ++reg) {
                    const int r = rbase + reg;
                    if (r < nrows) Cf[(size_t)r * DO + col] = acc[mf][nf][reg] + b;
                }
            }
        }
    }

    // ---- fp16 C: stage in LDS (reuse wlds), dump coalesced ----
    if (OUTF16) {
        __syncthreads();   // all waves done reading W from wlds
        #pragma unroll
        for (int nf = 0; nf < NF; ++nf) {
            const int col = nf * 16 + lr;
            const float b = BIAS ? bias[col] : 0.f;
            #pragma unroll
            for (int mf = 0; mf < 2; ++mf) {
                const int rl = wave * 32 + mf * 16 + kb * 4;
                #pragma unroll
                for (int reg = 0; reg < 4; ++reg)
                    wlds[(rl + reg) * DO + col] = (_Float16)(acc[mf][nf][reg] + b);
            }
        }
        __syncthreads();
        constexpr int DROW = DO / 8;
        #pragma unroll
        for (int i = 0; i < 128 * DROW / 256; ++i) {
            int c = t + i * 256;
            int row = c / DROW;
            int kc = c - row * DROW;
            int gr = rowblk * 128 + row;
            if (gr < nrows)
                *reinterpret_cast<f16x8*>(Ch + (size_t)gr * DO + kc * 8) =
                    *reinterpret_cast<const f16x8*>(&wlds[row * DO + kc * 8]);
        }
    }

    if (STATS) {
        __syncthreads();
        if (t < DO) {
            atomicAdd(&sums_out[t], ssum[t]);
            atomicAdd(&sums_out[DO + t], sqsum[t]);
        }
    }
}

// ------------------------- BN stats over fp16 (layer 2) --------------------

template <int DO>
__global__ __launch_bounds__(256) void stats_h(const __half* __restrict__ H,
                                               float* __restrict__ sums, int nrows) {
    constexpr int G = 256 / DO;
    int t = threadIdx.x;
    int col = t % DO;
    int grp = t / DO;
    float s = 0.f, s2 = 0.f;
    for (int r = blockIdx.x * G + grp; r < nrows; r += gridDim.x * G) {
        float v = __half2float(H[(size_t)r * DO + col]);
        s += v;
        s2 = fmaf(v, v, s2);
    }
    __shared__ float sm[256], sm2[256];
    sm[t] = s;
    sm2[t] = s2;
    __syncthreads();
    if (grp == 0) {
        #pragma unroll
        for (int g = 1; g < G; ++g) {
            s += sm[g * DO + col];
            s2 += sm2[g * DO + col];
        }
        atomicAdd(&sums[col], s);
        atomicAdd(&sums[DO + col], s2);
    }
}

// ------------------------- host orchestration ------------------------------

static inline size_t align_up(size_t v, size_t a) { return (v + a - 1) & ~(a - 1); }

extern "C" void kernel_launch(void* const* d_in, const int* in_sizes, int n_in,
                              void* d_out, int out_size, void* d_ws, size_t ws_size,
                              hipStream_t stream) {
    const float* x = (const float*)d_in[0];
    const int* ei = (const int*)d_in[1];
    const int N = in_sizes[0] / 64;
    const int E = in_sizes[1] / 2;
    const int* src = ei;
    const int* dst = ei + E;

    const float* w1[3]; const float* b1[3]; const float* gg[3];
    const float* be[3]; const float* w2[3]; const float* b2[3];
    for (int l = 0; l < 3; ++l) {
        w1[l] = (const float*)d_in[2 + 6 * l + 0];
        b1[l] = (const float*)d_in[2 + 6 * l + 1];
        gg[l] = (const float*)d_in[2 + 6 * l + 2];
        be[l] = (const float*)d_in[2 + 6 * l + 3];
        w2[l] = (const float*)d_in[2 + 6 * l + 4];
        b2[l] = (const float*)d_in[2 + 6 * l + 5];
    }

    char* ws = (char*)d_ws;
    size_t off = 0;
    auto alloc = [&](size_t bytes) {
        void* p = ws + off;
        off = align_up(off + bytes, 64);
        return p;
    };
    __half* HA   = (__half*)alloc((size_t)N * 128 * 2);  // t0 / pre1 / h2
    __half* HB   = (__half*)alloc((size_t)N * 128 * 2);  // h1 / t1
    __half* XH   = (__half*)alloc((size_t)N * 64 * 2);   // x fp16, later z
    __half* PRE0 = (__half*)alloc((size_t)N * 64 * 2);   // pre0, later y
    int* srcs   = (int*)alloc((size_t)E * 4);
    int* starts = (int*)alloc((size_t)(N + 1) * 4);
    int* cursor = (int*)alloc((size_t)N * 4);
    int* bsum   = (int*)alloc(256 * 4);
    float* sums = (float*)alloc(256 * 4);

    const int wdims[6][2] = {{64,128},{128,128},{128,128},{128,128},{128,64},{64,64}};
    const float* wsrc[6] = {w1[0], w2[0], w1[1], w2[1], w1[2], w2[2]};
    short* wh[6];
    WsArgs wa;
    int base = 0;
    for (int i = 0; i < 6; ++i) {
        int elems = wdims[i][0] * wdims[i][1];
        wh[i] = (short*)alloc((size_t)elems * 2);
        wa.w[i] = wsrc[i]; wa.hi[i] = wh[i];
        wa.K[i] = wdims[i][0]; wa.Nc[i] = wdims[i][1]; wa.base[i] = base;
        base += elems;
    }
    wa.total = base;
    wa.dstp = dst;
    wa.deg = cursor;
    wa.E = E;
    wa.xf = x;
    wa.xh = XH;
    wa.nx4 = N * 16;
    (void)ws_size; (void)n_in; (void)out_size;

    const float inv_n = 1.0f / (float)N;

    // ---- zero cursor; weight convert + histogram + x->fp16 ----
    hipMemsetAsync(cursor, 0, (size_t)N * 4, stream);
    wsplit_all<<<4096, 256, 0, stream>>>(wa);

    // ---- CSR scan + fill ----
    int chunks = (N + 1023) / 1024;
    scan_part_kernel<<<chunks, 1024, 0, stream>>>(cursor, starts, bsum, N);
    scan_add_kernel<<<chunks, 1024, 0, stream>>>(starts, cursor, bsum, N, E, chunks);
    int P = N / 8;
    if (P < 1) P = 1;
    fill_part_kernel<<<1024, 256, 0, stream>>>(src, dst, cursor, srcs, E, P);

    const int nb = (N + 127) / 128;

    // ---- layer 0 ----
    gather_hh<64, false, true><<<N, 64, 0, stream>>>(
        XH, starts, srcs, nullptr, PRE0, sums, 256, N);
    gemm16<64, 128, false, true, true, true><<<nb, 256, 0, stream>>>(
        PRE0, wh[0], b1[0], nullptr, nullptr, nullptr, inv_n,
        nullptr, HA, sums, N);
    gemm16<128, 128, true, false, true, true><<<nb, 256, 0, stream>>>(
        HA, wh[1], b2[0], sums, gg[0], be[0], inv_n,
        nullptr, HB, nullptr, N);

    // ---- layer 1 ----
    gather_hh<128, false, true><<<N, 64, 0, stream>>>(
        HB, starts, srcs, nullptr, HA, sums, 256, N);
    gemm16<128, 128, false, true, true, true><<<nb, 256, 0, stream>>>(
        HA, wh[2], b1[1], nullptr, nullptr, nullptr, inv_n,
        nullptr, HB, sums, N);
    gemm16<128, 128, true, false, true, true><<<nb, 256, 0, stream>>>(
        HB, wh[3], b2[1], sums, gg[1], be[1], inv_n,
        nullptr, HA, nullptr, N);

    // ---- layer 2 (aggregation commuted through W1) ----
    gemm16<128, 64, false, false, false, true><<<nb, 256, 0, stream>>>(
        HA, wh[4], nullptr, nullptr, nullptr, nullptr, inv_n,
        nullptr, XH, nullptr, N);
    gather_hh<64, true, true><<<N, 64, 0, stream>>>(
        XH, starts, srcs, b1[2], PRE0, sums, 128, N);
    stats_h<64><<<512, 256, 0, stream>>>(PRE0, sums, N);
    gemm16<64, 64, true, false, true, false><<<nb, 256, 0, stream>>>(
        PRE0, wh[5], b2[2], sums, gg[2], be[2], inv_n,
        (float*)d_out, nullptr, nullptr, N);
}